// Round 5
// baseline (1931.733 us; speedup 1.0000x reference)
//
#include <hip/hip_runtime.h>

#define BATCH 256
#define L 1024
#define C 16
#define NLEV 10
#define POOL 512          // pooled cols per level per channel
#define PCOLS 5632        // 11*512
#define FDIM 90112        // C*PCOLS
#define H1 128
#define H2 64

#define MT 2
#define KT 128
#define KCH 704           // FDIM/KT
#define KB 32
#define MTILE 128

#define BUFSZ 16896       // 16384 + 16384/32 skew pad
#define SSTR 512          // pooled staging stride (floats)
#define TREE_LDS_BYTES ((2*BUFSZ + 1024 + 32) * 4)

typedef float f32x4 __attribute__((ext_vector_type(4)));

__device__ __forceinline__ int skew(int i) { return i + (i >> 5); }

// ---------------- Kernel 1: leaf + hierarchical conv tree + pooling ----------------
__launch_bounds__(512)
__global__ void tree_kernel(const float* __restrict__ x,
                            const float* __restrict__ leaf_w,
                            const float* __restrict__ leaf_b,
                            const float* __restrict__ conv_w,
                            const float* __restrict__ conv_b,
                            const float* __restrict__ bn_gamma,
                            const float* __restrict__ bn_beta,
                            const float* __restrict__ node_w,
                            float* __restrict__ pooled) {
    extern __shared__ float smem[];
    float* buf0 = smem;
    float* buf1 = smem + BUFSZ;
    float4* w4  = (float4*)(smem + 2 * BUFSZ);
    float* sc   = smem + 2 * BUFSZ + 1024;
    float* bt   = sc + 16;

    const int b   = blockIdx.x;
    const int tid = threadIdx.x;

    // lane mapping for vectorized pooled stores:
    // thread -> channel pc, 4 x float4 at cols r*128 + (tid&31)*4  (r=0..3)
    const int pc   = tid >> 5;        // channel 0..15
    const int pcol = (tid & 31) * 4;  // col group within 128-col stripe

    // stage conv weights as float4 (3 taps + pad) for broadcast b128 reads
    if (tid < 256) {
        int o = tid >> 4, i = tid & 15;
        const float* wp = conv_w + o * 48 + i * 3;
        w4[tid] = make_float4(wp[0], wp[1], wp[2], 0.f);
    }
    if (tid < 16) {
        float s = bn_gamma[tid] / sqrtf(1.0f + 1e-5f);
        sc[tid] = s;
        bt[tid] = conv_b[tid] * s + bn_beta[tid];   // folded (conv_b*scale + beta)
    }

    // ---- leaf stage: thread owns leaf pair (2*tid, 2*tid+1), all channels ----
    {
        const float2 xv  = *(const float2*)(x + b * L + 2 * tid);
        const float2 nw2 = *(const float2*)(node_w + 2 * tid);
        const float4* lwa = (const float4*)(leaf_w + 32 * tid);
        const float4* lba = (const float4*)(leaf_b + 32 * tid);
        float* stage = buf1;          // free before level 0
#pragma unroll
        for (int q = 0; q < 4; ++q) {
            float4 w0 = lwa[q],     bb0 = lba[q];       // row 2*tid, c=4q..4q+3
            float4 w1 = lwa[q + 4], bb1 = lba[q + 4];   // row 2*tid+1
            float v0[4], v1[4];
            v0[0] = (xv.x * w0.x + bb0.x) * nw2.x;  v1[0] = (xv.y * w1.x + bb1.x) * nw2.y;
            v0[1] = (xv.x * w0.y + bb0.y) * nw2.x;  v1[1] = (xv.y * w1.y + bb1.y) * nw2.y;
            v0[2] = (xv.x * w0.z + bb0.z) * nw2.x;  v1[2] = (xv.y * w1.z + bb1.z) * nw2.y;
            v0[3] = (xv.x * w0.w + bb0.w) * nw2.x;  v1[3] = (xv.y * w1.w + bb1.w) * nw2.y;
#pragma unroll
            for (int j = 0; j < 4; ++j) {
                int c = 4 * q + j;
                buf0[skew((2 * tid) * C + c)]     = v0[j];
                buf0[skew((2 * tid + 1) * C + c)] = v1[j];
                stage[c * SSTR + tid] = fmaxf(v0[j], v1[j]);
            }
        }
        __syncthreads();
#pragma unroll
        for (int r = 0; r < 4; ++r) {
            f32x4 pv = *(f32x4*)&stage[pc * SSTR + r * 128 + pcol];
            *(f32x4*)(pooled + b * FDIM + pc * PCOLS + r * 128 + pcol) = pv;
        }
        __syncthreads();   // protect stage (buf1 = level-0 bout) from overwrite
    }

    // ---- 10 levels ----
    float* bin  = buf0;
    float* bout = buf1;
    int noff = L;                       // node_weights offset for this level
    for (int d = 0; d < NLEV; ++d) {
        const int Lk = 1 << d;
        const int L2 = Lk << 1;
        const int n2 = tid >> d;
        const int tp = tid & (Lk - 1);
        const int t0 = tp << 1;

        // sample positions tt = t0-1 .. t0+2 ; clamp for safe (masked) addressing
        int adr[4];
        const bool ok0 = (t0 > 0);
        const bool ok3 = (t0 + 2 < L2);
#pragma unroll
        for (int r = 0; r < 4; ++r) {
            int tt = t0 - 1 + r;
            int ttc = tt < 0 ? 0 : (tt > L2 - 1 ? L2 - 1 : tt);
            int node = 2 * n2 + (ttc >= Lk ? 1 : 0);
            adr[r] = node * (C * Lk) + (ttc & (Lk - 1));
        }

        float acc0[C], acc1[C];
#pragma unroll
        for (int co = 0; co < C; ++co) { acc0[co] = 0.f; acc1[co] = 0.f; }

#pragma unroll
        for (int ci = 0; ci < C; ++ci) {
            const int o = ci * Lk;
            float vm1 = ok0 ? bin[skew(adr[0] + o)] : 0.f;
            float v0  = bin[skew(adr[1] + o)];
            float v1  = bin[skew(adr[2] + o)];
            float v2  = ok3 ? bin[skew(adr[3] + o)] : 0.f;
#pragma unroll
            for (int co = 0; co < C; ++co) {
                float4 w = w4[co * C + ci];   // uniform address -> broadcast
                acc0[co] = fmaf(w.x, vm1, fmaf(w.y, v0, fmaf(w.z, v1, acc0[co])));
                acc1[co] = fmaf(w.x, v0,  fmaf(w.y, v1, fmaf(w.z, v2, acc1[co])));
            }
        }

        const float nwv = node_w[noff + n2];
        const int ob = n2 * (C * L2) + t0;
        float poolv[C];
#pragma unroll
        for (int co = 0; co < C; ++co) {
            float z0 = fmaxf(fmaf(sc[co], acc0[co], bt[co]), 0.f) * nwv;
            float z1 = fmaxf(fmaf(sc[co], acc1[co], bt[co]), 0.f) * nwv;
            bout[skew(ob + co * L2)]     = z0;
            bout[skew(ob + co * L2 + 1)] = z1;
            poolv[co] = fmaxf(z0, z1);
        }
        __syncthreads();                     // all bin reads done
        float* stage = bin;                  // reuse dead input buffer
#pragma unroll
        for (int co = 0; co < C; ++co)
            stage[co * SSTR + tid] = poolv[co];
        __syncthreads();
        {
            float* pbase = pooled + b * FDIM + pc * PCOLS + (d + 1) * POOL;
#pragma unroll
            for (int r = 0; r < 4; ++r) {
                f32x4 pv = *(f32x4*)&stage[pc * SSTR + r * 128 + pcol];
                *(f32x4*)(pbase + r * 128 + pcol) = pv;
            }
        }
        __syncthreads();                     // protect stage (= next level's bout)
        float* t = bin; bin = bout; bout = t;
        noff += (L >> (d + 1));
    }
}

// ---------------- Kernel 2: fc1 split-K partial GEMM ----------------
// grid = MT * KT blocks; block (mt,kt) computes partial[kt][b0:b0+128][0:128]
__launch_bounds__(512)
__global__ void fc1_partial(const float* __restrict__ pooled,
                            const float* __restrict__ w1,
                            float* __restrict__ partial) {
    __shared__ float a_s[MTILE][36];
    __shared__ float w_s[H1][36];

    const int mt = blockIdx.x & (MT - 1);
    const int kt = blockIdx.x >> 1;
    const int b0 = mt * MTILE;
    const int k0 = kt * KCH;

    const int tid = threadIdx.x;
    const int bg = tid >> 4;       // 0..31 -> rows bg*4 + i
    const int jg = tid & 15;       // 0..15 -> cols jg*8 + j

    const int srow = tid >> 3;     // 0..63
    const int scol = (tid & 7) * 4;

    float acc[4][8];
#pragma unroll
    for (int i = 0; i < 4; ++i)
#pragma unroll
        for (int j = 0; j < 8; ++j) acc[i][j] = 0.f;

    for (int kb = 0; kb < KCH; kb += KB) {
        __syncthreads();
        // stage A (pooled rows) and W (fc1_w rows), XOR-swizzled columns
#pragma unroll
        for (int rr = 0; rr < 2; ++rr) {
            int row = rr * 64 + srow;
            float4 av = *(const float4*)(pooled + (long)(b0 + row) * FDIM + k0 + kb + scol);
            *(float4*)&a_s[row][scol ^ (((row >> 2) & 7) << 2)] = av;
            float4 wv = *(const float4*)(w1 + (long)row * FDIM + k0 + kb + scol);
            *(float4*)&w_s[row][scol ^ (((row >> 3) & 7) << 2)] = wv;
        }
        __syncthreads();

#pragma unroll
        for (int kk = 0; kk < KB; kk += 4) {
            float4 av[4], wv[8];
            const int ca = kk ^ ((bg & 7) << 2);
            const int cw = kk ^ ((jg & 7) << 2);
#pragma unroll
            for (int i = 0; i < 4; ++i) av[i] = *(const float4*)&a_s[bg * 4 + i][ca];
#pragma unroll
            for (int j = 0; j < 8; ++j) wv[j] = *(const float4*)&w_s[jg * 8 + j][cw];
#pragma unroll
            for (int i = 0; i < 4; ++i)
#pragma unroll
                for (int j = 0; j < 8; ++j) {
                    acc[i][j] = fmaf(av[i].x, wv[j].x,
                                fmaf(av[i].y, wv[j].y,
                                fmaf(av[i].z, wv[j].z,
                                fmaf(av[i].w, wv[j].w, acc[i][j]))));
                }
        }
    }

#pragma unroll
    for (int i = 0; i < 4; ++i) {
        int brow = b0 + bg * 4 + i;
        float4 o0 = make_float4(acc[i][0], acc[i][1], acc[i][2], acc[i][3]);
        float4 o1 = make_float4(acc[i][4], acc[i][5], acc[i][6], acc[i][7]);
        float* p = partial + (long)kt * (BATCH * H1) + brow * H1 + jg * 8;
        *(float4*)(p)     = o0;
        *(float4*)(p + 4) = o1;
    }
}

// ---------------- Kernel 3: reduce partials + fc1 bias/relu + fc2 + fc3 ----------------
__launch_bounds__(128)
__global__ void fc_tail(const float* __restrict__ partial,
                        const float* __restrict__ fc1_b,
                        const float* __restrict__ w2,
                        const float* __restrict__ b2,
                        const float* __restrict__ w3,
                        const float* __restrict__ b3,
                        float* __restrict__ out) {
    __shared__ float h1_s[H1];
    __shared__ float w2_s[H2 * 129];

    const int b = blockIdx.x;
    const int t = threadIdx.x;

    float s = 0.f;
    for (int kt = 0; kt < KT; ++kt)
        s += partial[(long)kt * (BATCH * H1) + b * H1 + t];
    h1_s[t] = fmaxf(s + fc1_b[t], 0.f);

    for (int i = t; i < H2 * H1; i += 128) {
        int j = i >> 7, k = i & 127;
        w2_s[j * 129 + k] = w2[i];
    }
    __syncthreads();

    if (t < 64) {
        float a2 = 0.f;
#pragma unroll 8
        for (int k = 0; k < H1; ++k) a2 = fmaf(h1_s[k], w2_s[t * 129 + k], a2);
        float h2 = fmaxf(a2 + b2[t], 0.f);
        float r = h2 * w3[t];
#pragma unroll
        for (int off = 32; off > 0; off >>= 1) r += __shfl_down(r, off);
        if (t == 0) out[b] = r + b3[0];
    }
}

extern "C" void kernel_launch(void* const* d_in, const int* in_sizes, int n_in,
                              void* d_out, int out_size, void* d_ws, size_t ws_size,
                              hipStream_t stream) {
    const float* x        = (const float*)d_in[0];
    const float* leaf_w   = (const float*)d_in[1];
    const float* leaf_b   = (const float*)d_in[2];
    const float* conv_w   = (const float*)d_in[3];
    const float* conv_b   = (const float*)d_in[4];
    const float* bn_gamma = (const float*)d_in[5];
    const float* bn_beta  = (const float*)d_in[6];
    const float* node_w   = (const float*)d_in[7];
    const float* fc1_w    = (const float*)d_in[8];
    const float* fc1_b    = (const float*)d_in[9];
    const float* fc2_w    = (const float*)d_in[10];
    const float* fc2_b    = (const float*)d_in[11];
    const float* fc3_w    = (const float*)d_in[12];
    const float* fc3_b    = (const float*)d_in[13];

    float* pooled  = (float*)d_ws;                        // 256*90112 floats = 92.3 MB
    float* partial = pooled + (long)BATCH * FDIM;         // 128*256*128 floats = 16.8 MB

    (void)hipFuncSetAttribute((const void*)tree_kernel,
                        hipFuncAttributeMaxDynamicSharedMemorySize, TREE_LDS_BYTES);

    tree_kernel<<<BATCH, 512, TREE_LDS_BYTES, stream>>>(
        x, leaf_w, leaf_b, conv_w, conv_b, bn_gamma, bn_beta, node_w, pooled);

    fc1_partial<<<MT * KT, 512, 0, stream>>>(pooled, fc1_w, partial);

    fc_tail<<<BATCH, 128, 0, stream>>>(partial, fc1_b, fc2_w, fc2_b, fc3_w, fc3_b,
                                       (float*)d_out);
}

// Round 6
// 1185.942 us; speedup vs baseline: 1.6289x; 1.6289x over previous
//
#include <hip/hip_runtime.h>

#define BATCH 256
#define L 1024
#define C 16
#define NLEV 10
#define POOL 512          // pooled cols per level per channel
#define PCOLS 5632        // 11*512
#define FDIM 90112        // C*PCOLS
#define H1 128
#define H2 64

#define MT 2
#define KT 128
#define KCH 704           // FDIM/KT
#define KB 32
#define MTILE 128

#define BUFSZ 16896       // 16384 + 16384/32 skew pad
#define SSTR 512          // pooled staging stride (floats)
#define TREE_LDS_BYTES ((2*BUFSZ + 1024 + 32) * 4)

typedef float f32x4 __attribute__((ext_vector_type(4)));

__device__ __forceinline__ int skew(int i) { return i + (i >> 5); }

// ---------------- Kernel 1: leaf + hierarchical conv tree + pooling ----------------
// launch_bounds(512, 2): 8 waves/block, min 2 waves/EU -> VGPR cap 256 (no spill).
__launch_bounds__(512, 2)
__global__ void tree_kernel(const float* __restrict__ x,
                            const float* __restrict__ leaf_w,
                            const float* __restrict__ leaf_b,
                            const float* __restrict__ conv_w,
                            const float* __restrict__ conv_b,
                            const float* __restrict__ bn_gamma,
                            const float* __restrict__ bn_beta,
                            const float* __restrict__ node_w,
                            float* __restrict__ pooled) {
    extern __shared__ float smem[];
    float* buf0 = smem;
    float* buf1 = smem + BUFSZ;
    float4* w4  = (float4*)(smem + 2 * BUFSZ);
    float* sc   = smem + 2 * BUFSZ + 1024;
    float* bt   = sc + 16;

    const int b   = blockIdx.x;
    const int tid = threadIdx.x;

    // lane mapping for vectorized pooled stores:
    // thread -> channel pc, 4 x float4 at cols r*128 + (tid&31)*4  (r=0..3)
    const int pc   = tid >> 5;        // channel 0..15
    const int pcol = (tid & 31) * 4;  // col group within 128-col stripe

    // stage conv weights as float4 (3 taps + pad) for broadcast b128 reads
    if (tid < 256) {
        int o = tid >> 4, i = tid & 15;
        const float* wp = conv_w + o * 48 + i * 3;
        w4[tid] = make_float4(wp[0], wp[1], wp[2], 0.f);
    }
    if (tid < 16) {
        float s = bn_gamma[tid] / sqrtf(1.0f + 1e-5f);
        sc[tid] = s;
        bt[tid] = conv_b[tid] * s + bn_beta[tid];   // folded (conv_b*scale + beta)
    }

    // ---- leaf stage: thread owns leaf pair (2*tid, 2*tid+1), all channels ----
    {
        const float2 xv  = *(const float2*)(x + b * L + 2 * tid);
        const float2 nw2 = *(const float2*)(node_w + 2 * tid);
        const float4* lwa = (const float4*)(leaf_w + 32 * tid);
        const float4* lba = (const float4*)(leaf_b + 32 * tid);
        float* stage = buf1;          // free before level 0
#pragma unroll
        for (int q = 0; q < 4; ++q) {
            float4 w0 = lwa[q],     bb0 = lba[q];       // row 2*tid, c=4q..4q+3
            float4 w1 = lwa[q + 4], bb1 = lba[q + 4];   // row 2*tid+1
            float v0[4], v1[4];
            v0[0] = (xv.x * w0.x + bb0.x) * nw2.x;  v1[0] = (xv.y * w1.x + bb1.x) * nw2.y;
            v0[1] = (xv.x * w0.y + bb0.y) * nw2.x;  v1[1] = (xv.y * w1.y + bb1.y) * nw2.y;
            v0[2] = (xv.x * w0.z + bb0.z) * nw2.x;  v1[2] = (xv.y * w1.z + bb1.z) * nw2.y;
            v0[3] = (xv.x * w0.w + bb0.w) * nw2.x;  v1[3] = (xv.y * w1.w + bb1.w) * nw2.y;
#pragma unroll
            for (int j = 0; j < 4; ++j) {
                int c = 4 * q + j;
                buf0[skew((2 * tid) * C + c)]     = v0[j];
                buf0[skew((2 * tid + 1) * C + c)] = v1[j];
                stage[c * SSTR + tid] = fmaxf(v0[j], v1[j]);
            }
        }
        __syncthreads();
#pragma unroll
        for (int r = 0; r < 4; ++r) {
            f32x4 pv = *(f32x4*)&stage[pc * SSTR + r * 128 + pcol];
            *(f32x4*)(pooled + b * FDIM + pc * PCOLS + r * 128 + pcol) = pv;
        }
        __syncthreads();   // protect stage (buf1 = level-0 bout) from overwrite
    }

    // ---- 10 levels ----
    float* bin  = buf0;
    float* bout = buf1;
    int noff = L;                       // node_weights offset for this level
    for (int d = 0; d < NLEV; ++d) {
        const int Lk = 1 << d;
        const int L2 = Lk << 1;
        const int n2 = tid >> d;
        const int tp = tid & (Lk - 1);
        const int t0 = tp << 1;

        // sample positions tt = t0-1 .. t0+2 ; clamp for safe (masked) addressing
        int adr[4];
        const bool ok0 = (t0 > 0);
        const bool ok3 = (t0 + 2 < L2);
#pragma unroll
        for (int r = 0; r < 4; ++r) {
            int tt = t0 - 1 + r;
            int ttc = tt < 0 ? 0 : (tt > L2 - 1 ? L2 - 1 : tt);
            int node = 2 * n2 + (ttc >= Lk ? 1 : 0);
            adr[r] = node * (C * Lk) + (ttc & (Lk - 1));
        }

        const float nwv = node_w[noff + n2];
        const int ob = n2 * (C * L2) + t0;
        float poolv[C];

        // two passes of 8 output channels: halves register pressure (16 accs live)
#pragma unroll
        for (int half = 0; half < 2; ++half) {
            float acc0[8], acc1[8];
#pragma unroll
            for (int co = 0; co < 8; ++co) { acc0[co] = 0.f; acc1[co] = 0.f; }

#pragma unroll
            for (int ci = 0; ci < C; ++ci) {
                const int o = ci * Lk;
                float vm1 = ok0 ? bin[skew(adr[0] + o)] : 0.f;
                float v0  = bin[skew(adr[1] + o)];
                float v1  = bin[skew(adr[2] + o)];
                float v2  = ok3 ? bin[skew(adr[3] + o)] : 0.f;
#pragma unroll
                for (int co = 0; co < 8; ++co) {
                    float4 w = w4[(half * 8 + co) * C + ci];   // uniform -> broadcast
                    acc0[co] = fmaf(w.x, vm1, fmaf(w.y, v0, fmaf(w.z, v1, acc0[co])));
                    acc1[co] = fmaf(w.x, v0,  fmaf(w.y, v1, fmaf(w.z, v2, acc1[co])));
                }
            }

#pragma unroll
            for (int co = 0; co < 8; ++co) {
                const int c = half * 8 + co;
                float z0 = fmaxf(fmaf(sc[c], acc0[co], bt[c]), 0.f) * nwv;
                float z1 = fmaxf(fmaf(sc[c], acc1[co], bt[c]), 0.f) * nwv;
                bout[skew(ob + c * L2)]     = z0;
                bout[skew(ob + c * L2 + 1)] = z1;
                poolv[c] = fmaxf(z0, z1);
            }
        }

        __syncthreads();                     // all bin reads done
        float* stage = bin;                  // reuse dead input buffer
#pragma unroll
        for (int co = 0; co < C; ++co)
            stage[co * SSTR + tid] = poolv[co];
        __syncthreads();
        {
            float* pbase = pooled + b * FDIM + pc * PCOLS + (d + 1) * POOL;
#pragma unroll
            for (int r = 0; r < 4; ++r) {
                f32x4 pv = *(f32x4*)&stage[pc * SSTR + r * 128 + pcol];
                *(f32x4*)(pbase + r * 128 + pcol) = pv;
            }
        }
        __syncthreads();                     // protect stage (= next level's bout)
        float* t = bin; bin = bout; bout = t;
        noff += (L >> (d + 1));
    }
}

// ---------------- Kernel 2: fc1 split-K partial GEMM ----------------
// grid = MT * KT blocks; block (mt,kt) computes partial[kt][b0:b0+128][0:128]
__launch_bounds__(512)
__global__ void fc1_partial(const float* __restrict__ pooled,
                            const float* __restrict__ w1,
                            float* __restrict__ partial) {
    __shared__ float a_s[MTILE][36];
    __shared__ float w_s[H1][36];

    const int mt = blockIdx.x & (MT - 1);
    const int kt = blockIdx.x >> 1;
    const int b0 = mt * MTILE;
    const int k0 = kt * KCH;

    const int tid = threadIdx.x;
    const int bg = tid >> 4;       // 0..31 -> rows bg*4 + i
    const int jg = tid & 15;       // 0..15 -> cols jg*8 + j

    const int srow = tid >> 3;     // 0..63
    const int scol = (tid & 7) * 4;

    float acc[4][8];
#pragma unroll
    for (int i = 0; i < 4; ++i)
#pragma unroll
        for (int j = 0; j < 8; ++j) acc[i][j] = 0.f;

    for (int kb = 0; kb < KCH; kb += KB) {
        __syncthreads();
        // stage A (pooled rows) and W (fc1_w rows), XOR-swizzled columns
#pragma unroll
        for (int rr = 0; rr < 2; ++rr) {
            int row = rr * 64 + srow;
            float4 av = *(const float4*)(pooled + (long)(b0 + row) * FDIM + k0 + kb + scol);
            *(float4*)&a_s[row][scol ^ (((row >> 2) & 7) << 2)] = av;
            float4 wv = *(const float4*)(w1 + (long)row * FDIM + k0 + kb + scol);
            *(float4*)&w_s[row][scol ^ (((row >> 3) & 7) << 2)] = wv;
        }
        __syncthreads();

#pragma unroll
        for (int kk = 0; kk < KB; kk += 4) {
            float4 av[4], wv[8];
            const int ca = kk ^ ((bg & 7) << 2);
            const int cw = kk ^ ((jg & 7) << 2);
#pragma unroll
            for (int i = 0; i < 4; ++i) av[i] = *(const float4*)&a_s[bg * 4 + i][ca];
#pragma unroll
            for (int j = 0; j < 8; ++j) wv[j] = *(const float4*)&w_s[jg * 8 + j][cw];
#pragma unroll
            for (int i = 0; i < 4; ++i)
#pragma unroll
                for (int j = 0; j < 8; ++j) {
                    acc[i][j] = fmaf(av[i].x, wv[j].x,
                                fmaf(av[i].y, wv[j].y,
                                fmaf(av[i].z, wv[j].z,
                                fmaf(av[i].w, wv[j].w, acc[i][j]))));
                }
        }
    }

#pragma unroll
    for (int i = 0; i < 4; ++i) {
        int brow = b0 + bg * 4 + i;
        float4 o0 = make_float4(acc[i][0], acc[i][1], acc[i][2], acc[i][3]);
        float4 o1 = make_float4(acc[i][4], acc[i][5], acc[i][6], acc[i][7]);
        float* p = partial + (long)kt * (BATCH * H1) + brow * H1 + jg * 8;
        *(float4*)(p)     = o0;
        *(float4*)(p + 4) = o1;
    }
}

// ---------------- Kernel 3: reduce partials + fc1 bias/relu + fc2 + fc3 ----------------
__launch_bounds__(128)
__global__ void fc_tail(const float* __restrict__ partial,
                        const float* __restrict__ fc1_b,
                        const float* __restrict__ w2,
                        const float* __restrict__ b2,
                        const float* __restrict__ w3,
                        const float* __restrict__ b3,
                        float* __restrict__ out) {
    __shared__ float h1_s[H1];
    __shared__ float w2_s[H2 * 129];

    const int b = blockIdx.x;
    const int t = threadIdx.x;

    float s = 0.f;
    for (int kt = 0; kt < KT; ++kt)
        s += partial[(long)kt * (BATCH * H1) + b * H1 + t];
    h1_s[t] = fmaxf(s + fc1_b[t], 0.f);

    for (int i = t; i < H2 * H1; i += 128) {
        int j = i >> 7, k = i & 127;
        w2_s[j * 129 + k] = w2[i];
    }
    __syncthreads();

    if (t < 64) {
        float a2 = 0.f;
#pragma unroll 8
        for (int k = 0; k < H1; ++k) a2 = fmaf(h1_s[k], w2_s[t * 129 + k], a2);
        float h2 = fmaxf(a2 + b2[t], 0.f);
        float r = h2 * w3[t];
#pragma unroll
        for (int off = 32; off > 0; off >>= 1) r += __shfl_down(r, off);
        if (t == 0) out[b] = r + b3[0];
    }
}

extern "C" void kernel_launch(void* const* d_in, const int* in_sizes, int n_in,
                              void* d_out, int out_size, void* d_ws, size_t ws_size,
                              hipStream_t stream) {
    const float* x        = (const float*)d_in[0];
    const float* leaf_w   = (const float*)d_in[1];
    const float* leaf_b   = (const float*)d_in[2];
    const float* conv_w   = (const float*)d_in[3];
    const float* conv_b   = (const float*)d_in[4];
    const float* bn_gamma = (const float*)d_in[5];
    const float* bn_beta  = (const float*)d_in[6];
    const float* node_w   = (const float*)d_in[7];
    const float* fc1_w    = (const float*)d_in[8];
    const float* fc1_b    = (const float*)d_in[9];
    const float* fc2_w    = (const float*)d_in[10];
    const float* fc2_b    = (const float*)d_in[11];
    const float* fc3_w    = (const float*)d_in[12];
    const float* fc3_b    = (const float*)d_in[13];

    float* pooled  = (float*)d_ws;                        // 256*90112 floats = 92.3 MB
    float* partial = pooled + (long)BATCH * FDIM;         // 128*256*128 floats = 16.8 MB

    (void)hipFuncSetAttribute((const void*)tree_kernel,
                        hipFuncAttributeMaxDynamicSharedMemorySize, TREE_LDS_BYTES);

    tree_kernel<<<BATCH, 512, TREE_LDS_BYTES, stream>>>(
        x, leaf_w, leaf_b, conv_w, conv_b, bn_gamma, bn_beta, node_w, pooled);

    fc1_partial<<<MT * KT, 512, 0, stream>>>(pooled, fc1_w, partial);

    fc_tail<<<BATCH, 128, 0, stream>>>(partial, fc1_b, fc2_w, fc2_b, fc3_w, fc3_b,
                                       (float*)d_out);
}

// Round 7
// 256.319 us; speedup vs baseline: 7.5365x; 4.6268x over previous
//
#include <hip/hip_runtime.h>

#define BATCH 256
#define L 1024
#define C 16
#define NLEV 10
#define POOL 512          // pooled cols per level per channel
#define PCOLS 5632        // 11*512
#define FDIM 90112        // C*PCOLS
#define H1 128
#define H2 64

#define MT 2
#define KT 128
#define KCH 704           // FDIM/KT
#define KB 32
#define MTILE 128

#define BUFSZ 16896       // 16384 + 16384/32 skew pad
#define SSTR 512          // pooled staging stride (floats)
#define TREE_LDS_BYTES ((2*BUFSZ + 1024 + 32) * 4)

typedef float f32x4 __attribute__((ext_vector_type(4)));

__device__ __forceinline__ int skew(int i) { return i + (i >> 5); }

// ---------------- Kernel 1: leaf + hierarchical conv tree + pooling ----------------
__launch_bounds__(512, 2)
__global__ void tree_kernel(const float* __restrict__ x,
                            const float* __restrict__ leaf_w,
                            const float* __restrict__ leaf_b,
                            const float* __restrict__ conv_w,
                            const float* __restrict__ conv_b,
                            const float* __restrict__ bn_gamma,
                            const float* __restrict__ bn_beta,
                            const float* __restrict__ node_w,
                            float* __restrict__ pooled) {
    extern __shared__ float smem[];
    float* buf0 = smem;
    float* buf1 = smem + BUFSZ;
    float4* w4  = (float4*)(smem + 2 * BUFSZ);
    float* sc   = smem + 2 * BUFSZ + 1024;
    float* bt   = sc + 16;

    const int b   = blockIdx.x;
    const int tid = threadIdx.x;

    // lane mapping for vectorized pooled stores:
    // thread -> channel pc, 4 x float4 at cols r*128 + (tid&31)*4  (r=0..3)
    const int pc   = tid >> 5;        // channel 0..15
    const int pcol = (tid & 31) * 4;  // col group within 128-col stripe

    // stage conv weights as float4 (3 taps + pad) for broadcast b128 reads
    if (tid < 256) {
        int o = tid >> 4, i = tid & 15;
        const float* wp = conv_w + o * 48 + i * 3;
        w4[tid] = make_float4(wp[0], wp[1], wp[2], 0.f);
    }
    if (tid < 16) {
        float s = bn_gamma[tid] / sqrtf(1.0f + 1e-5f);
        sc[tid] = s;
        bt[tid] = conv_b[tid] * s + bn_beta[tid];   // folded (conv_b*scale + beta)
    }

    // ---- leaf stage: thread owns leaf pair (2*tid, 2*tid+1), all channels ----
    {
        const float2 xv  = *(const float2*)(x + b * L + 2 * tid);
        const float2 nw2 = *(const float2*)(node_w + 2 * tid);
        const float4* lwa = (const float4*)(leaf_w + 32 * tid);
        const float4* lba = (const float4*)(leaf_b + 32 * tid);
        float* stage = buf1;          // free before level 0
#pragma unroll 1
        for (int q = 0; q < 4; ++q) {
            float4 w0 = lwa[q],     bb0 = lba[q];       // row 2*tid, c=4q..4q+3
            float4 w1 = lwa[q + 4], bb1 = lba[q + 4];   // row 2*tid+1
            float v0[4], v1[4];
            v0[0] = (xv.x * w0.x + bb0.x) * nw2.x;  v1[0] = (xv.y * w1.x + bb1.x) * nw2.y;
            v0[1] = (xv.x * w0.y + bb0.y) * nw2.x;  v1[1] = (xv.y * w1.y + bb1.y) * nw2.y;
            v0[2] = (xv.x * w0.z + bb0.z) * nw2.x;  v1[2] = (xv.y * w1.z + bb1.z) * nw2.y;
            v0[3] = (xv.x * w0.w + bb0.w) * nw2.x;  v1[3] = (xv.y * w1.w + bb1.w) * nw2.y;
#pragma unroll
            for (int j = 0; j < 4; ++j) {
                int c = 4 * q + j;
                buf0[skew((2 * tid) * C + c)]     = v0[j];
                buf0[skew((2 * tid + 1) * C + c)] = v1[j];
                stage[c * SSTR + tid] = fmaxf(v0[j], v1[j]);
            }
        }
        __syncthreads();
#pragma unroll
        for (int r = 0; r < 4; ++r) {
            f32x4 pv = *(f32x4*)&stage[pc * SSTR + r * 128 + pcol];
            *(f32x4*)(pooled + b * FDIM + pc * PCOLS + r * 128 + pcol) = pv;
        }
        __syncthreads();   // protect stage (buf1 = level-0 bout) from overwrite
    }

    // ---- 10 levels ----
    float* bin  = buf0;
    float* bout = buf1;
    int noff = L;                       // node_weights offset for this level
    for (int d = 0; d < NLEV; ++d) {
        const int Lk = 1 << d;
        const int L2 = Lk << 1;
        const int n2 = tid >> d;
        const int tp = tid & (Lk - 1);
        const int t0 = tp << 1;

        // sample positions tt = t0-1 .. t0+2 ; clamp for safe (masked) addressing
        int adr[4];
        const bool ok0 = (t0 > 0);
        const bool ok3 = (t0 + 2 < L2);
#pragma unroll
        for (int r = 0; r < 4; ++r) {
            int tt = t0 - 1 + r;
            int ttc = tt < 0 ? 0 : (tt > L2 - 1 ? L2 - 1 : tt);
            int node = 2 * n2 + (ttc >= Lk ? 1 : 0);
            adr[r] = node * (C * Lk) + (ttc & (Lk - 1));
        }

        const float nwv = node_w[noff + n2];
        const int ob = n2 * (C * L2) + t0;
        float poolv[C];

        // two passes of 8 output channels x 4 ci-chunks of 4:
        // #pragma unroll 1 on the chunk loop stops the compiler from hoisting
        // all 64 LDS loads -> live values stay ~45 VGPR, no scratch spill.
#pragma unroll 1
        for (int half = 0; half < 2; ++half) {
            float acc0[8], acc1[8];
#pragma unroll
            for (int co = 0; co < 8; ++co) { acc0[co] = 0.f; acc1[co] = 0.f; }

#pragma unroll 1
            for (int cic = 0; cic < 4; ++cic) {
#pragma unroll
                for (int ci4 = 0; ci4 < 4; ++ci4) {
                    const int ci = cic * 4 + ci4;
                    const int o = ci * Lk;
                    float vm1 = ok0 ? bin[skew(adr[0] + o)] : 0.f;
                    float v0  = bin[skew(adr[1] + o)];
                    float v1  = bin[skew(adr[2] + o)];
                    float v2  = ok3 ? bin[skew(adr[3] + o)] : 0.f;
#pragma unroll
                    for (int co = 0; co < 8; ++co) {
                        float4 w = w4[(half * 8 + co) * C + ci];   // LDS broadcast
                        acc0[co] = fmaf(w.x, vm1, fmaf(w.y, v0, fmaf(w.z, v1, acc0[co])));
                        acc1[co] = fmaf(w.x, v0,  fmaf(w.y, v1, fmaf(w.z, v2, acc1[co])));
                    }
                }
            }

#pragma unroll
            for (int co = 0; co < 8; ++co) {
                const int c = half * 8 + co;
                float z0 = fmaxf(fmaf(sc[c], acc0[co], bt[c]), 0.f) * nwv;
                float z1 = fmaxf(fmaf(sc[c], acc1[co], bt[c]), 0.f) * nwv;
                bout[skew(ob + c * L2)]     = z0;
                bout[skew(ob + c * L2 + 1)] = z1;
                poolv[c] = fmaxf(z0, z1);
            }
        }

        __syncthreads();                     // all bin reads done
        float* stage = bin;                  // reuse dead input buffer
#pragma unroll
        for (int co = 0; co < C; ++co)
            stage[co * SSTR + tid] = poolv[co];
        __syncthreads();
        {
            float* pbase = pooled + b * FDIM + pc * PCOLS + (d + 1) * POOL;
#pragma unroll
            for (int r = 0; r < 4; ++r) {
                f32x4 pv = *(f32x4*)&stage[pc * SSTR + r * 128 + pcol];
                *(f32x4*)(pbase + r * 128 + pcol) = pv;
            }
        }
        __syncthreads();                     // protect stage (= next level's bout)
        float* t = bin; bin = bout; bout = t;
        noff += (L >> (d + 1));
    }
}

// ---------------- Kernel 2: fc1 split-K partial GEMM ----------------
// grid = MT * KT blocks; block (mt,kt) computes partial[kt][b0:b0+128][0:128]
__launch_bounds__(512)
__global__ void fc1_partial(const float* __restrict__ pooled,
                            const float* __restrict__ w1,
                            float* __restrict__ partial) {
    __shared__ float a_s[MTILE][36];
    __shared__ float w_s[H1][36];

    const int mt = blockIdx.x & (MT - 1);
    const int kt = blockIdx.x >> 1;
    const int b0 = mt * MTILE;
    const int k0 = kt * KCH;

    const int tid = threadIdx.x;
    const int bg = tid >> 4;       // 0..31 -> rows bg*4 + i
    const int jg = tid & 15;       // 0..15 -> cols jg*8 + j

    const int srow = tid >> 3;     // 0..63
    const int scol = (tid & 7) * 4;

    float acc[4][8];
#pragma unroll
    for (int i = 0; i < 4; ++i)
#pragma unroll
        for (int j = 0; j < 8; ++j) acc[i][j] = 0.f;

    for (int kb = 0; kb < KCH; kb += KB) {
        __syncthreads();
        // stage A (pooled rows) and W (fc1_w rows), XOR-swizzled columns
#pragma unroll
        for (int rr = 0; rr < 2; ++rr) {
            int row = rr * 64 + srow;
            float4 av = *(const float4*)(pooled + (long)(b0 + row) * FDIM + k0 + kb + scol);
            *(float4*)&a_s[row][scol ^ (((row >> 2) & 7) << 2)] = av;
            float4 wv = *(const float4*)(w1 + (long)row * FDIM + k0 + kb + scol);
            *(float4*)&w_s[row][scol ^ (((row >> 3) & 7) << 2)] = wv;
        }
        __syncthreads();

#pragma unroll
        for (int kk = 0; kk < KB; kk += 4) {
            float4 av[4], wv[8];
            const int ca = kk ^ ((bg & 7) << 2);
            const int cw = kk ^ ((jg & 7) << 2);
#pragma unroll
            for (int i = 0; i < 4; ++i) av[i] = *(const float4*)&a_s[bg * 4 + i][ca];
#pragma unroll
            for (int j = 0; j < 8; ++j) wv[j] = *(const float4*)&w_s[jg * 8 + j][cw];
#pragma unroll
            for (int i = 0; i < 4; ++i)
#pragma unroll
                for (int j = 0; j < 8; ++j) {
                    acc[i][j] = fmaf(av[i].x, wv[j].x,
                                fmaf(av[i].y, wv[j].y,
                                fmaf(av[i].z, wv[j].z,
                                fmaf(av[i].w, wv[j].w, acc[i][j]))));
                }
        }
    }

#pragma unroll
    for (int i = 0; i < 4; ++i) {
        int brow = b0 + bg * 4 + i;
        float4 o0 = make_float4(acc[i][0], acc[i][1], acc[i][2], acc[i][3]);
        float4 o1 = make_float4(acc[i][4], acc[i][5], acc[i][6], acc[i][7]);
        float* p = partial + (long)kt * (BATCH * H1) + brow * H1 + jg * 8;
        *(float4*)(p)     = o0;
        *(float4*)(p + 4) = o1;
    }
}

// ---------------- Kernel 3: reduce partials + fc1 bias/relu + fc2 + fc3 ----------------
__launch_bounds__(128)
__global__ void fc_tail(const float* __restrict__ partial,
                        const float* __restrict__ fc1_b,
                        const float* __restrict__ w2,
                        const float* __restrict__ b2,
                        const float* __restrict__ w3,
                        const float* __restrict__ b3,
                        float* __restrict__ out) {
    __shared__ float h1_s[H1];
    __shared__ float w2_s[H2 * 129];

    const int b = blockIdx.x;
    const int t = threadIdx.x;

    float s = 0.f;
    for (int kt = 0; kt < KT; ++kt)
        s += partial[(long)kt * (BATCH * H1) + b * H1 + t];
    h1_s[t] = fmaxf(s + fc1_b[t], 0.f);

    for (int i = t; i < H2 * H1; i += 128) {
        int j = i >> 7, k = i & 127;
        w2_s[j * 129 + k] = w2[i];
    }
    __syncthreads();

    if (t < 64) {
        float a2 = 0.f;
#pragma unroll 8
        for (int k = 0; k < H1; ++k) a2 = fmaf(h1_s[k], w2_s[t * 129 + k], a2);
        float h2 = fmaxf(a2 + b2[t], 0.f);
        float r = h2 * w3[t];
#pragma unroll
        for (int off = 32; off > 0; off >>= 1) r += __shfl_down(r, off);
        if (t == 0) out[b] = r + b3[0];
    }
}

extern "C" void kernel_launch(void* const* d_in, const int* in_sizes, int n_in,
                              void* d_out, int out_size, void* d_ws, size_t ws_size,
                              hipStream_t stream) {
    const float* x        = (const float*)d_in[0];
    const float* leaf_w   = (const float*)d_in[1];
    const float* leaf_b   = (const float*)d_in[2];
    const float* conv_w   = (const float*)d_in[3];
    const float* conv_b   = (const float*)d_in[4];
    const float* bn_gamma = (const float*)d_in[5];
    const float* bn_beta  = (const float*)d_in[6];
    const float* node_w   = (const float*)d_in[7];
    const float* fc1_w    = (const float*)d_in[8];
    const float* fc1_b    = (const float*)d_in[9];
    const float* fc2_w    = (const float*)d_in[10];
    const float* fc2_b    = (const float*)d_in[11];
    const float* fc3_w    = (const float*)d_in[12];
    const float* fc3_b    = (const float*)d_in[13];

    float* pooled  = (float*)d_ws;                        // 256*90112 floats = 92.3 MB
    float* partial = pooled + (long)BATCH * FDIM;         // 128*256*128 floats = 16.8 MB

    (void)hipFuncSetAttribute((const void*)tree_kernel,
                        hipFuncAttributeMaxDynamicSharedMemorySize, TREE_LDS_BYTES);

    tree_kernel<<<BATCH, 512, TREE_LDS_BYTES, stream>>>(
        x, leaf_w, leaf_b, conv_w, conv_b, bn_gamma, bn_beta, node_w, pooled);

    fc1_partial<<<MT * KT, 512, 0, stream>>>(pooled, fc1_w, partial);

    fc_tail<<<BATCH, 128, 0, stream>>>(partial, fc1_b, fc2_w, fc2_b, fc3_w, fc3_b,
                                       (float*)d_out);
}

// Round 8
// 226.833 us; speedup vs baseline: 8.5161x; 1.1300x over previous
//
#include <hip/hip_runtime.h>

#define BATCH 256
#define L 1024
#define C 16
#define NLEV 10
#define POOL 512          // pooled cols per level per channel
#define PCOLS 5632        // 11*512
#define FDIM 90112        // C*PCOLS
#define H1 128
#define H2 64

#define MT 2
#define KT 128
#define KCH 704           // FDIM/KT
#define KB 32
#define MTILE 128

#define BUFSZ 16896       // 16384 + 16384/32 skew pad
#define SSTR 512          // pooled staging stride (floats)
#define TREE_LDS_BYTES ((2*BUFSZ + 32) * 4)

typedef float f32x4 __attribute__((ext_vector_type(4)));

__device__ __forceinline__ int skew(int i) { return i + (i >> 5); }

// ---------------- Kernel 1: leaf + hierarchical conv tree + pooling ----------------
__launch_bounds__(512, 2)
__global__ void tree_kernel(const float* __restrict__ x,
                            const float* __restrict__ leaf_w,
                            const float* __restrict__ leaf_b,
                            const float* __restrict__ conv_w,
                            const float* __restrict__ conv_b,
                            const float* __restrict__ bn_gamma,
                            const float* __restrict__ bn_beta,
                            const float* __restrict__ node_w,
                            float* __restrict__ pooled) {
    extern __shared__ float smem[];
    float* buf0 = smem;
    float* buf1 = smem + BUFSZ;
    float* sc   = smem + 2 * BUFSZ;
    float* bt   = sc + 16;

    const int b   = blockIdx.x;
    const int tid = threadIdx.x;

    // lane mapping for vectorized pooled stores:
    // thread -> channel pc, 4 x float4 at cols r*128 + (tid&31)*4  (r=0..3)
    const int pc   = tid >> 5;        // channel 0..15
    const int pcol = (tid & 31) * 4;  // col group within 128-col stripe

    if (tid < 16) {
        float s = bn_gamma[tid] / sqrtf(1.0f + 1e-5f);
        sc[tid] = s;
        bt[tid] = conv_b[tid] * s + bn_beta[tid];   // folded (conv_b*scale + beta)
    }

    // ---- leaf stage: thread owns leaf pair (2*tid, 2*tid+1), all channels ----
    {
        const float2 xv  = *(const float2*)(x + b * L + 2 * tid);
        const float2 nw2 = *(const float2*)(node_w + 2 * tid);
        const float4* lwa = (const float4*)(leaf_w + 32 * tid);
        const float4* lba = (const float4*)(leaf_b + 32 * tid);
        float* stage = buf1;          // free before level 0
#pragma unroll 1
        for (int q = 0; q < 4; ++q) {
            float4 w0 = lwa[q],     bb0 = lba[q];       // row 2*tid, c=4q..4q+3
            float4 w1 = lwa[q + 4], bb1 = lba[q + 4];   // row 2*tid+1
            float v0[4], v1[4];
            v0[0] = (xv.x * w0.x + bb0.x) * nw2.x;  v1[0] = (xv.y * w1.x + bb1.x) * nw2.y;
            v0[1] = (xv.x * w0.y + bb0.y) * nw2.x;  v1[1] = (xv.y * w1.y + bb1.y) * nw2.y;
            v0[2] = (xv.x * w0.z + bb0.z) * nw2.x;  v1[2] = (xv.y * w1.z + bb1.z) * nw2.y;
            v0[3] = (xv.x * w0.w + bb0.w) * nw2.x;  v1[3] = (xv.y * w1.w + bb1.w) * nw2.y;
#pragma unroll
            for (int j = 0; j < 4; ++j) {
                int c = 4 * q + j;
                buf0[skew((2 * tid) * C + c)]     = v0[j];
                buf0[skew((2 * tid + 1) * C + c)] = v1[j];
                stage[c * SSTR + tid] = fmaxf(v0[j], v1[j]);
            }
        }
        __syncthreads();
#pragma unroll
        for (int r = 0; r < 4; ++r) {
            f32x4 pv = *(f32x4*)&stage[pc * SSTR + r * 128 + pcol];
            *(f32x4*)(pooled + b * FDIM + pc * PCOLS + r * 128 + pcol) = pv;
        }
        __syncthreads();   // protect stage (buf1 = level-0 bout) from overwrite
    }

    // ---- 10 levels ----
    float* bin  = buf0;
    float* bout = buf1;
    int noff = L;                       // node_weights offset for this level
    for (int d = 0; d < NLEV; ++d) {
        const int Lk = 1 << d;
        const int L2 = Lk << 1;
        const int n2 = tid >> d;
        const int tp = tid & (Lk - 1);
        const int t0 = tp << 1;

        // sample positions tt = t0-1 .. t0+2 ; clamp for safe (masked) addressing
        int adr[4];
        const bool ok0 = (t0 > 0);
        const bool ok3 = (t0 + 2 < L2);
#pragma unroll
        for (int r = 0; r < 4; ++r) {
            int tt = t0 - 1 + r;
            int ttc = tt < 0 ? 0 : (tt > L2 - 1 ? L2 - 1 : tt);
            int node = 2 * n2 + (ttc >= Lk ? 1 : 0);
            adr[r] = node * (C * Lk) + (ttc & (Lk - 1));
        }

        const float nwv = node_w[noff + n2];
        const int ob = n2 * (C * L2) + t0;
        float poolv[C];

        // two passes of 8 output channels x 4 ci-chunks of 4 (unroll 1 bounds
        // register lifetimes -> no spill). Weights read scalar-uniform from
        // GLOBAL (s_load path, L1-cached) -> zero LDS-pipe cost.
#pragma unroll 1
        for (int half = 0; half < 2; ++half) {
            float acc0[8], acc1[8];
#pragma unroll
            for (int co = 0; co < 8; ++co) { acc0[co] = 0.f; acc1[co] = 0.f; }

#pragma unroll 1
            for (int cic = 0; cic < 4; ++cic) {
#pragma unroll
                for (int ci4 = 0; ci4 < 4; ++ci4) {
                    const int ci = cic * 4 + ci4;
                    const int o = ci * Lk;
                    float vm1 = ok0 ? bin[skew(adr[0] + o)] : 0.f;
                    float v0  = bin[skew(adr[1] + o)];
                    float v1  = bin[skew(adr[2] + o)];
                    float v2  = ok3 ? bin[skew(adr[3] + o)] : 0.f;
#pragma unroll
                    for (int co = 0; co < 8; ++co) {
                        const float* wp = conv_w + (((half * 8 + co) * C) + ci) * 3;
                        const float wx = wp[0], wy = wp[1], wz = wp[2]; // uniform -> SGPR
                        acc0[co] = fmaf(wx, vm1, fmaf(wy, v0, fmaf(wz, v1, acc0[co])));
                        acc1[co] = fmaf(wx, v0,  fmaf(wy, v1, fmaf(wz, v2, acc1[co])));
                    }
                }
            }

#pragma unroll
            for (int co = 0; co < 8; ++co) {
                const int c = half * 8 + co;
                float z0 = fmaxf(fmaf(sc[c], acc0[co], bt[c]), 0.f) * nwv;
                float z1 = fmaxf(fmaf(sc[c], acc1[co], bt[c]), 0.f) * nwv;
                bout[skew(ob + c * L2)]     = z0;
                bout[skew(ob + c * L2 + 1)] = z1;
                poolv[c] = fmaxf(z0, z1);
            }
        }

        __syncthreads();                     // all bin reads done
        float* stage = bin;                  // reuse dead input buffer
#pragma unroll
        for (int co = 0; co < C; ++co)
            stage[co * SSTR + tid] = poolv[co];
        __syncthreads();
        {
            float* pbase = pooled + b * FDIM + pc * PCOLS + (d + 1) * POOL;
#pragma unroll
            for (int r = 0; r < 4; ++r) {
                f32x4 pv = *(f32x4*)&stage[pc * SSTR + r * 128 + pcol];
                *(f32x4*)(pbase + r * 128 + pcol) = pv;
            }
        }
        __syncthreads();                     // protect stage (= next level's bout)
        float* t = bin; bin = bout; bout = t;
        noff += (L >> (d + 1));
    }
}

// ---------------- Kernel 2: fc1 split-K partial GEMM ----------------
// grid = MT * KT blocks; block (mt,kt) computes partial[kt][b0:b0+128][0:128]
__launch_bounds__(512)
__global__ void fc1_partial(const float* __restrict__ pooled,
                            const float* __restrict__ w1,
                            float* __restrict__ partial) {
    __shared__ float a_s[MTILE][36];
    __shared__ float w_s[H1][36];

    const int mt = blockIdx.x & (MT - 1);
    const int kt = blockIdx.x >> 1;
    const int b0 = mt * MTILE;
    const int k0 = kt * KCH;

    const int tid = threadIdx.x;
    const int bg = tid >> 4;       // 0..31 -> rows bg*4 + i
    const int jg = tid & 15;       // 0..15 -> cols jg*8 + j

    const int srow = tid >> 3;     // 0..63
    const int scol = (tid & 7) * 4;

    float acc[4][8];
#pragma unroll
    for (int i = 0; i < 4; ++i)
#pragma unroll
        for (int j = 0; j < 8; ++j) acc[i][j] = 0.f;

    for (int kb = 0; kb < KCH; kb += KB) {
        __syncthreads();
        // stage A (pooled rows) and W (fc1_w rows), XOR-swizzled columns
#pragma unroll
        for (int rr = 0; rr < 2; ++rr) {
            int row = rr * 64 + srow;
            float4 av = *(const float4*)(pooled + (long)(b0 + row) * FDIM + k0 + kb + scol);
            *(float4*)&a_s[row][scol ^ (((row >> 2) & 7) << 2)] = av;
            float4 wv = *(const float4*)(w1 + (long)row * FDIM + k0 + kb + scol);
            *(float4*)&w_s[row][scol ^ (((row >> 3) & 7) << 2)] = wv;
        }
        __syncthreads();

#pragma unroll
        for (int kk = 0; kk < KB; kk += 4) {
            float4 av[4], wv[8];
            const int ca = kk ^ ((bg & 7) << 2);
            const int cw = kk ^ ((jg & 7) << 2);
#pragma unroll
            for (int i = 0; i < 4; ++i) av[i] = *(const float4*)&a_s[bg * 4 + i][ca];
#pragma unroll
            for (int j = 0; j < 8; ++j) wv[j] = *(const float4*)&w_s[jg * 8 + j][cw];
#pragma unroll
            for (int i = 0; i < 4; ++i)
#pragma unroll
                for (int j = 0; j < 8; ++j) {
                    acc[i][j] = fmaf(av[i].x, wv[j].x,
                                fmaf(av[i].y, wv[j].y,
                                fmaf(av[i].z, wv[j].z,
                                fmaf(av[i].w, wv[j].w, acc[i][j]))));
                }
        }
    }

#pragma unroll
    for (int i = 0; i < 4; ++i) {
        int brow = b0 + bg * 4 + i;
        float4 o0 = make_float4(acc[i][0], acc[i][1], acc[i][2], acc[i][3]);
        float4 o1 = make_float4(acc[i][4], acc[i][5], acc[i][6], acc[i][7]);
        float* p = partial + (long)kt * (BATCH * H1) + brow * H1 + jg * 8;
        *(float4*)(p)     = o0;
        *(float4*)(p + 4) = o1;
    }
}

// ---------------- Kernel 3: reduce partials + fc1 bias/relu + fc2 + fc3 ----------------
__launch_bounds__(128)
__global__ void fc_tail(const float* __restrict__ partial,
                        const float* __restrict__ fc1_b,
                        const float* __restrict__ w2,
                        const float* __restrict__ b2,
                        const float* __restrict__ w3,
                        const float* __restrict__ b3,
                        float* __restrict__ out) {
    __shared__ float h1_s[H1];
    __shared__ float w2_s[H2 * 129];

    const int b = blockIdx.x;
    const int t = threadIdx.x;

    float s = 0.f;
    for (int kt = 0; kt < KT; ++kt)
        s += partial[(long)kt * (BATCH * H1) + b * H1 + t];
    h1_s[t] = fmaxf(s + fc1_b[t], 0.f);

    for (int i = t; i < H2 * H1; i += 128) {
        int j = i >> 7, k = i & 127;
        w2_s[j * 129 + k] = w2[i];
    }
    __syncthreads();

    if (t < 64) {
        float a2 = 0.f;
#pragma unroll 8
        for (int k = 0; k < H1; ++k) a2 = fmaf(h1_s[k], w2_s[t * 129 + k], a2);
        float h2 = fmaxf(a2 + b2[t], 0.f);
        float r = h2 * w3[t];
#pragma unroll
        for (int off = 32; off > 0; off >>= 1) r += __shfl_down(r, off);
        if (t == 0) out[b] = r + b3[0];
    }
}

extern "C" void kernel_launch(void* const* d_in, const int* in_sizes, int n_in,
                              void* d_out, int out_size, void* d_ws, size_t ws_size,
                              hipStream_t stream) {
    const float* x        = (const float*)d_in[0];
    const float* leaf_w   = (const float*)d_in[1];
    const float* leaf_b   = (const float*)d_in[2];
    const float* conv_w   = (const float*)d_in[3];
    const float* conv_b   = (const float*)d_in[4];
    const float* bn_gamma = (const float*)d_in[5];
    const float* bn_beta  = (const float*)d_in[6];
    const float* node_w   = (const float*)d_in[7];
    const float* fc1_w    = (const float*)d_in[8];
    const float* fc1_b    = (const float*)d_in[9];
    const float* fc2_w    = (const float*)d_in[10];
    const float* fc2_b    = (const float*)d_in[11];
    const float* fc3_w    = (const float*)d_in[12];
    const float* fc3_b    = (const float*)d_in[13];

    float* pooled  = (float*)d_ws;                        // 256*90112 floats = 92.3 MB
    float* partial = pooled + (long)BATCH * FDIM;         // 128*256*128 floats = 16.8 MB

    (void)hipFuncSetAttribute((const void*)tree_kernel,
                        hipFuncAttributeMaxDynamicSharedMemorySize, TREE_LDS_BYTES);

    tree_kernel<<<BATCH, 512, TREE_LDS_BYTES, stream>>>(
        x, leaf_w, leaf_b, conv_w, conv_b, bn_gamma, bn_beta, node_w, pooled);

    fc1_partial<<<MT * KT, 512, 0, stream>>>(pooled, fc1_w, partial);

    fc_tail<<<BATCH, 128, 0, stream>>>(partial, fc1_b, fc2_w, fc2_b, fc3_w, fc3_b,
                                       (float*)d_out);
}